// Round 7
// baseline (356.651 us; speedup 1.0000x reference)
//
#include <hip/hip_runtime.h>
#include <hip/hip_bf16.h>

// B=4, NV=50000, NRINGS=3, NDIRS=16, NF=16. All f32 except expmap(int32).
// MFMA: per vertex D[16d x 16f] = A[16d x 144k] * W[144k x 16f], k = dd*9 + q.
// R13 = R12 (1-wave blocks, 127.8us) + ONE change: neighbor gather is a
// single UNGUARDED global_load_dwordx4 (16B, 12B used) per neighbor instead
// of 3 scalar dwords. Rationale: divergent-gather TA address processing is
// the largest modeled resource (~45% busy: 9 insts x 64 lane-segments per
// staging wave); x,y,z of one neighbor share a cache line, so 3 insts -> 1
// cuts gather TA events ~3x. R11's x4 attempt regressed, but it was bundled
// with a per-gather exec-mask guard branch + launch_bounds change; here the
// guard is REMOVED: worst case (nb=199999) reads 4B past bp's 2,400,000B,
// and hipMalloc pads to >=page granularity (2,400,256B), so the 16B load
// stays in the mapped allocation; the 4th lane-element is never used.
// Carried: 1-wave blocks (R12, -4us), CP1=295 (R11, conflicts halved).
// Closed paths: operand swap (R9 wrong results), LDS-transpose epilogue
// (R10 -12us), store coalescing (R10: stores not the bottleneck).
#define NBATCH 4
#define NV     50000
#define VPB    4           // vertices per block (1 wave x 4 vertices)
#define VST    304         // per-vertex stride = 2*VST elems
#define CP1    295         // copy-1 element offset: odd, ==7 mod 32 (bank fix)

typedef __attribute__((ext_vector_type(8))) short short8;
typedef __attribute__((ext_vector_type(4))) float floatx4;
// 4B-aligned float4 view: backend allows misaligned (align>=4) dwordx4 on
// global, so this still emits ONE global_load_dwordx4.
typedef __attribute__((ext_vector_type(4), aligned(4))) float floatx4u;

// ---- pre-kernel: build per-lane W fragments (bf16) into d_ws ----
// layout: lane*40 + kc*8 ushorts (16B per chunk, 80B per lane, 5120B total)
__global__ void build_wfrag(const float* __restrict__ kw,
                            unsigned short* __restrict__ wbuf) {
    const int lane = threadIdx.x;      // 0..63
    const int fcol = lane & 15;
    const int quad = lane >> 4;
    #pragma unroll
    for (int kc = 0; kc < 5; ++kc) {
        unsigned short v[8];
        #pragma unroll
        for (int j = 0; j < 8; ++j) {
            int k = kc * 32 + quad * 8 + j;
            unsigned short b = 0;
            if (k < 144) {
                int dd = k / 9;
                int q  = k - dd * 9;
                int r  = q / 3;
                int c  = q - r * 3;
                __hip_bfloat16 h = __float2bfloat16(kw[((r * 16 + dd) * 3 + c) * 16 + fcol]);
                __builtin_memcpy(&b, &h, 2);
            }
            v[j] = b;
        }
        __builtin_memcpy(wbuf + lane * 40 + kc * 8, v, 16);
    }
}

__global__ __launch_bounds__(64, 8)
void input3d_mfma(const float* __restrict__ bp,     // (B,NV,3)
                  const float* __restrict__ fr,     // (B,NV,3,3)
                  const int2*  __restrict__ em,     // (B,NV,3,16) int pairs
                  const unsigned short* __restrict__ wbuf, // prebuilt W frags
                  const float* __restrict__ bias,   // (16)
                  float*       __restrict__ out)    // (B,NV,16,16)
{
    __shared__ __align__(16) unsigned short yls[VPB * 2 * VST];   // 4864 B

    const int tid  = threadIdx.x;      // 0..63 (one wave)
    const int bv0  = blockIdx.x * VPB;
    const int lane = tid;
    const int fcol = lane & 15;
    const int quad = lane >> 4;

    // ---- load prebuilt W fragments: 5 x dwordx4 ----
    union WU { unsigned short s[8]; short8 v; };
    WU wf[5];
    const unsigned short* wl = wbuf + lane * 40;
    #pragma unroll
    for (int kc = 0; kc < 5; ++kc)
        __builtin_memcpy(&wf[kc].s[0], wl + kc * 8, 16);
    const float bsf = bias[fcol];

    // ---- staging: thread = (v = tid>>4, dir = tid&15) ----
    {
        const int v   = tid >> 4;      // 0..3
        const int dir = tid & 15;
        const int bv  = bv0 + v;
        float F[9];
        __builtin_memcpy(&F[0], fr + (size_t)bv * 9, 16);
        __builtin_memcpy(&F[4], fr + (size_t)bv * 9 + 4, 16);
        F[8] = fr[(size_t)bv * 9 + 8];
        const float c0 = bp[bv * 3 + 0];
        const float c1 = bp[bv * 3 + 1];
        const float c2 = bp[bv * 3 + 2];

        unsigned short val[9];
        #pragma unroll
        for (int r = 0; r < 3; ++r) {
            int2 e  = em[bv * 48 + r * 16 + dir];
            int nb  = e.x * NV + e.y;
            // ONE dwordx4 per neighbor (12B used). Unguarded: see header note.
            floatx4u g = *reinterpret_cast<const floatx4u*>(bp + (size_t)nb * 3);
            float dx = g[0] - c0;
            float dy = g[1] - c1;
            float dz = g[2] - c2;
            #pragma unroll
            for (int c = 0; c < 3; ++c) {
                float yv = F[c * 3 + 0] * dx + F[c * 3 + 1] * dy + F[c * 3 + 2] * dz;
                __hip_bfloat16 h = __float2bfloat16(yv);
                unsigned short us;
                __builtin_memcpy(&us, &h, 2);
                val[r * 3 + c] = us;
            }
        }

        // packed 9-element group writes (4 x b32 + 1 x u16 per group)
        unsigned short* buf = &yls[v * 2 * VST];
        unsigned int pe[4], po[4];
        #pragma unroll
        for (int i = 0; i < 4; ++i) {
            pe[i] = (unsigned int)val[2 * i]     | ((unsigned int)val[2 * i + 1] << 16);
            po[i] = (unsigned int)val[2 * i + 1] | ((unsigned int)val[2 * i + 2] << 16);
        }
        const int n0 = dir * 9;
        // even-start group: dwords at s, tail u16 at s+8
        auto storeE = [&](int s) {
            unsigned int* p = (unsigned int*)(buf + s);
            p[0] = pe[0]; p[1] = pe[1]; p[2] = pe[2]; p[3] = pe[3];
            buf[s + 8] = val[8];
        };
        // odd-start group: head u16 at s, dwords at s+1
        auto storeO = [&](int s) {
            buf[s] = val[0];
            unsigned int* p = (unsigned int*)(buf + s + 1);
            p[0] = po[0]; p[1] = po[1]; p[2] = po[2]; p[3] = po[3];
        };
        if (dir & 1) {                 // n0 odd
            storeO(n0);
            storeE(CP1 + n0);          // 295+odd = even start
            if (dir < 15) { storeO(n0 + 144); storeE(CP1 + n0 + 144); }
        } else {                       // n0 even
            storeE(n0);
            storeO(CP1 + n0);          // 295+even = odd start
            if (dir < 15) { storeE(n0 + 144); storeO(CP1 + n0 + 144); }
        }
    }
    // single-wave workgroup: s_barrier is immediate; kept purely as a
    // correct, compiler-visible memory fence for the LDS write->read handoff.
    __syncthreads();

    // ---- this wave: 4 vertices, 5 MFMA each (K=144 exact) ----
    floatx4 acc[4] = {{0.f,0.f,0.f,0.f},{0.f,0.f,0.f,0.f},
                      {0.f,0.f,0.f,0.f},{0.f,0.f,0.f,0.f}};
    const unsigned short* abase[4];
    #pragma unroll
    for (int i = 0; i < 4; ++i) {
        abase[i] = &yls[i * 2 * VST + ((fcol & 1) ? CP1 : 0) + 9 * fcol];
    }
    #pragma unroll
    for (int kc = 0; kc < 4; ++kc) {
        const int s = kc * 32 + quad * 8;
        #pragma unroll
        for (int i = 0; i < 4; ++i) {
            const unsigned int* pa = (const unsigned int*)(abase[i] + s);
            union { unsigned int u[4]; short8 s8; } a;
            a.u[0] = pa[0]; a.u[1] = pa[1]; a.u[2] = pa[2]; a.u[3] = pa[3];
            acc[i] = __builtin_amdgcn_mfma_f32_16x16x32_bf16(a.s8, wf[kc].v, acc[i], 0, 0, 0);
        }
    }
    {   // chunk 4: k = 128 + quad*8 + j; valid k<144 only for quads 0,1.
        const int s = 128 + quad * 8;
        #pragma unroll
        for (int i = 0; i < 4; ++i) {
            union { unsigned int u[4]; short8 s8; } a;
            if (quad < 2) {
                const unsigned int* pa = (const unsigned int*)(abase[i] + s);
                a.u[0] = pa[0]; a.u[1] = pa[1]; a.u[2] = pa[2]; a.u[3] = pa[3];
            } else {
                a.u[0] = 0; a.u[1] = 0; a.u[2] = 0; a.u[3] = 0;
            }
            acc[i] = __builtin_amdgcn_mfma_f32_16x16x32_bf16(a.s8, wf[4].v, acc[i], 0, 0, 0);
        }
    }

    // ---- epilogue: R6 scattered stores (proven fine; not the bottleneck) ----
    // C layout col=lane&15=f, row=quad*4+reg=d -> direct store.
    #pragma unroll
    for (int i = 0; i < 4; ++i) {
        int vg = bv0 + i;
        float* ob = out + (size_t)vg * 256;
        #pragma unroll
        for (int rr = 0; rr < 4; ++rr) {
            float o = acc[i][rr] + bsf;
            o = o > 0.f ? o : 0.f;
            ob[(quad * 4 + rr) * 16 + fcol] = o;
        }
    }
}

extern "C" void kernel_launch(void* const* d_in, const int* in_sizes, int n_in,
                              void* d_out, int out_size, void* d_ws, size_t ws_size,
                              hipStream_t stream) {
    const float* bp   = (const float*)d_in[0];
    const float* fr   = (const float*)d_in[1];
    const int2*  em   = (const int2*)d_in[2];
    const float* kw   = (const float*)d_in[3];
    const float* bias = (const float*)d_in[4];
    float* out = (float*)d_out;
    unsigned short* wbuf = (unsigned short*)d_ws;   // 5120 B used

    build_wfrag<<<1, 64, 0, stream>>>(kw, wbuf);

    const int total_bv = NBATCH * NV;          // 200000
    const int grid = total_bv / VPB;           // 50000 blocks (1 wave each)
    input3d_mfma<<<grid, 64, 0, stream>>>(bp, fr, em, wbuf, bias, out);
}

// Round 8
// 351.288 us; speedup vs baseline: 1.0153x; 1.0153x over previous
//
#include <hip/hip_runtime.h>
#include <hip/hip_bf16.h>

// B=4, NV=50000, NRINGS=3, NDIRS=16, NF=16. All f32 except expmap(int32).
// MFMA: per vertex D[16d x 16f] = A[16d x 144k] * W[144k x 16f], k = dd*9 + q.
// R14 = R12 logic with ONE structural change: VPB=8, 128-thread (2-wave)
// workgroups, grid=25000.
//   Hypothesis: CDNA caps resident workgroups per CU (~16). 64-thread WGs
//   (R12) then cap at 16 waves/CU (4/SIMD) -- half of the 256-thread config's
//   32 -- explaining why decoupling only bought 4us. 2-wave WGs give
//   16 WG x 2 waves = 32 waves/CU (full) with only pairwise coupling.
//   Staging stays wave-aligned: wave w stages v=4w..4w+3 (threads 64w..64w+63)
//   and consumes exactly those vertices; __syncthreads is a cheap 2-wave
//   fence. LDS 9728B x 16 WG = 155KB <= 160KB (exact fit).
// Carried: CP1=295 bank fix (R11, conflicts 1.44e7->7.2e6), 3-scalar-dword
//   gather (R13 killed dwordx4 AGAIN: +10us unguarded; closed for good).
// Closed paths: operand swap (R9, wrong results -- A-lane-map not pinned on
//   circulant A), LDS-transpose epilogue (R10, -12us), gather widening
//   (R11+R13), store coalescing (R10: stores are not the bottleneck).
#define NBATCH 4
#define NV     50000
#define VPB    8           // vertices per block (2 waves x 4 vertices)
#define VST    304         // per-vertex stride = 2*VST elems
#define CP1    295         // copy-1 element offset: odd, ==7 mod 32 (bank fix)

typedef __attribute__((ext_vector_type(8))) short short8;
typedef __attribute__((ext_vector_type(4))) float floatx4;

// ---- pre-kernel: build per-lane W fragments (bf16) into d_ws ----
// layout: lane*40 + kc*8 ushorts (16B per chunk, 80B per lane, 5120B total)
__global__ void build_wfrag(const float* __restrict__ kw,
                            unsigned short* __restrict__ wbuf) {
    const int lane = threadIdx.x;      // 0..63
    const int fcol = lane & 15;
    const int quad = lane >> 4;
    #pragma unroll
    for (int kc = 0; kc < 5; ++kc) {
        unsigned short v[8];
        #pragma unroll
        for (int j = 0; j < 8; ++j) {
            int k = kc * 32 + quad * 8 + j;
            unsigned short b = 0;
            if (k < 144) {
                int dd = k / 9;
                int q  = k - dd * 9;
                int r  = q / 3;
                int c  = q - r * 3;
                __hip_bfloat16 h = __float2bfloat16(kw[((r * 16 + dd) * 3 + c) * 16 + fcol]);
                __builtin_memcpy(&b, &h, 2);
            }
            v[j] = b;
        }
        __builtin_memcpy(wbuf + lane * 40 + kc * 8, v, 16);
    }
}

__global__ __launch_bounds__(128, 8)
void input3d_mfma(const float* __restrict__ bp,     // (B,NV,3)
                  const float* __restrict__ fr,     // (B,NV,3,3)
                  const int2*  __restrict__ em,     // (B,NV,3,16) int pairs
                  const unsigned short* __restrict__ wbuf, // prebuilt W frags
                  const float* __restrict__ bias,   // (16)
                  float*       __restrict__ out)    // (B,NV,16,16)
{
    __shared__ __align__(16) unsigned short yls[VPB * 2 * VST];   // 9728 B

    const int tid  = threadIdx.x;      // 0..127 (two waves)
    const int bv0  = blockIdx.x * VPB;
    const int lane = tid & 63;
    const int wid  = tid >> 6;         // 0..1
    const int fcol = lane & 15;
    const int quad = lane >> 4;

    // ---- load prebuilt W fragments: 5 x dwordx4 ----
    union WU { unsigned short s[8]; short8 v; };
    WU wf[5];
    const unsigned short* wl = wbuf + lane * 40;
    #pragma unroll
    for (int kc = 0; kc < 5; ++kc)
        __builtin_memcpy(&wf[kc].s[0], wl + kc * 8, 16);
    const float bsf = bias[fcol];

    // ---- staging: thread = (v = tid>>4, dir = tid&15); wave w -> v=4w..4w+3
    {
        const int v   = tid >> 4;      // 0..7
        const int dir = tid & 15;
        const int bv  = bv0 + v;
        float F[9];
        __builtin_memcpy(&F[0], fr + (size_t)bv * 9, 16);
        __builtin_memcpy(&F[4], fr + (size_t)bv * 9 + 4, 16);
        F[8] = fr[(size_t)bv * 9 + 8];
        const float c0 = bp[bv * 3 + 0];
        const float c1 = bp[bv * 3 + 1];
        const float c2 = bp[bv * 3 + 2];

        unsigned short val[9];
        #pragma unroll
        for (int r = 0; r < 3; ++r) {
            int2 e  = em[bv * 48 + r * 16 + dir];
            int nb  = e.x * NV + e.y;
            float dx = bp[nb * 3 + 0] - c0;
            float dy = bp[nb * 3 + 1] - c1;
            float dz = bp[nb * 3 + 2] - c2;
            #pragma unroll
            for (int c = 0; c < 3; ++c) {
                float yv = F[c * 3 + 0] * dx + F[c * 3 + 1] * dy + F[c * 3 + 2] * dz;
                __hip_bfloat16 h = __float2bfloat16(yv);
                unsigned short us;
                __builtin_memcpy(&us, &h, 2);
                val[r * 3 + c] = us;
            }
        }

        // packed 9-element group writes (4 x b32 + 1 x u16 per group)
        unsigned short* buf = &yls[v * 2 * VST];
        unsigned int pe[4], po[4];
        #pragma unroll
        for (int i = 0; i < 4; ++i) {
            pe[i] = (unsigned int)val[2 * i]     | ((unsigned int)val[2 * i + 1] << 16);
            po[i] = (unsigned int)val[2 * i + 1] | ((unsigned int)val[2 * i + 2] << 16);
        }
        const int n0 = dir * 9;
        // even-start group: dwords at s, tail u16 at s+8
        auto storeE = [&](int s) {
            unsigned int* p = (unsigned int*)(buf + s);
            p[0] = pe[0]; p[1] = pe[1]; p[2] = pe[2]; p[3] = pe[3];
            buf[s + 8] = val[8];
        };
        // odd-start group: head u16 at s, dwords at s+1
        auto storeO = [&](int s) {
            buf[s] = val[0];
            unsigned int* p = (unsigned int*)(buf + s + 1);
            p[0] = po[0]; p[1] = po[1]; p[2] = po[2]; p[3] = po[3];
        };
        if (dir & 1) {                 // n0 odd
            storeO(n0);
            storeE(CP1 + n0);          // 295+odd = even start
            if (dir < 15) { storeO(n0 + 144); storeE(CP1 + n0 + 144); }
        } else {                       // n0 even
            storeE(n0);
            storeO(CP1 + n0);          // 295+even = odd start
            if (dir < 15) { storeE(n0 + 144); storeO(CP1 + n0 + 144); }
        }
    }
    __syncthreads();   // 2-wave fence; each wave consumes only its own stage

    // ---- per wave: 4 vertices, 5 MFMA each (K=144 exact) ----
    floatx4 acc[4] = {{0.f,0.f,0.f,0.f},{0.f,0.f,0.f,0.f},
                      {0.f,0.f,0.f,0.f},{0.f,0.f,0.f,0.f}};
    const unsigned short* abase[4];
    #pragma unroll
    for (int i = 0; i < 4; ++i) {
        int v = wid * 4 + i;
        abase[i] = &yls[v * 2 * VST + ((fcol & 1) ? CP1 : 0) + 9 * fcol];
    }
    #pragma unroll
    for (int kc = 0; kc < 4; ++kc) {
        const int s = kc * 32 + quad * 8;
        #pragma unroll
        for (int i = 0; i < 4; ++i) {
            const unsigned int* pa = (const unsigned int*)(abase[i] + s);
            union { unsigned int u[4]; short8 s8; } a;
            a.u[0] = pa[0]; a.u[1] = pa[1]; a.u[2] = pa[2]; a.u[3] = pa[3];
            acc[i] = __builtin_amdgcn_mfma_f32_16x16x32_bf16(a.s8, wf[kc].v, acc[i], 0, 0, 0);
        }
    }
    {   // chunk 4: k = 128 + quad*8 + j; valid k<144 only for quads 0,1.
        const int s = 128 + quad * 8;
        #pragma unroll
        for (int i = 0; i < 4; ++i) {
            union { unsigned int u[4]; short8 s8; } a;
            if (quad < 2) {
                const unsigned int* pa = (const unsigned int*)(abase[i] + s);
                a.u[0] = pa[0]; a.u[1] = pa[1]; a.u[2] = pa[2]; a.u[3] = pa[3];
            } else {
                a.u[0] = 0; a.u[1] = 0; a.u[2] = 0; a.u[3] = 0;
            }
            acc[i] = __builtin_amdgcn_mfma_f32_16x16x32_bf16(a.s8, wf[4].v, acc[i], 0, 0, 0);
        }
    }

    // ---- epilogue: R6 scattered stores (proven fine; not the bottleneck) ----
    // C layout col=lane&15=f, row=quad*4+reg=d -> direct store.
    #pragma unroll
    for (int i = 0; i < 4; ++i) {
        int vg = bv0 + wid * 4 + i;
        float* ob = out + (size_t)vg * 256;
        #pragma unroll
        for (int rr = 0; rr < 4; ++rr) {
            float o = acc[i][rr] + bsf;
            o = o > 0.f ? o : 0.f;
            ob[(quad * 4 + rr) * 16 + fcol] = o;
        }
    }
}

extern "C" void kernel_launch(void* const* d_in, const int* in_sizes, int n_in,
                              void* d_out, int out_size, void* d_ws, size_t ws_size,
                              hipStream_t stream) {
    const float* bp   = (const float*)d_in[0];
    const float* fr   = (const float*)d_in[1];
    const int2*  em   = (const int2*)d_in[2];
    const float* kw   = (const float*)d_in[3];
    const float* bias = (const float*)d_in[4];
    float* out = (float*)d_out;
    unsigned short* wbuf = (unsigned short*)d_ws;   // 5120 B used

    build_wfrag<<<1, 64, 0, stream>>>(kw, wbuf);

    const int total_bv = NBATCH * NV;          // 200000
    const int grid = total_bv / VPB;           // 25000 blocks (2 waves each)
    input3d_mfma<<<grid, 128, 0, stream>>>(bp, fr, em, wbuf, bias, out);
}